// Round 1
// baseline (14613.832 us; speedup 1.0000x reference)
//
#include <hip/hip_runtime.h>
#include <hip/hip_bf16.h>
#include <cstdint>

#define B_    256
#define N_    343
#define C_    192
#define H_    6
#define D_    32
#define NW_   64
#define M_    (B_*N_)           // 87808 rows = B*N, divisible by 64 (1372 tiles)
#define NN_   (N_*N_)           // 117649
#define SCALE_ 0.17677669529663687f   // 32^-0.5

// ---------- bf16 helpers (OCP bf16 = top 16 bits of f32) ----------
__device__ __forceinline__ float b2f(unsigned short u) {
    return __uint_as_float(((unsigned int)u) << 16);
}
__device__ __forceinline__ unsigned short f2b(float f) {
    unsigned int x = __float_as_uint(f);
    x += 0x7FFFu + ((x >> 16) & 1u);   // round-to-nearest-even
    return (unsigned short)(x >> 16);
}

// ---------------------------------------------------------------------------
// Generic fp32 GEMM: out[m,j] = (sum_k X[m,k]*W[j,k] + bias[j]) * alpha
// X: [M_,K] row-major, W: [NJ,K] row-major (torch Linear weight layout).
// mode 0: scatter bf16 to out_b at [b,h,n,d] (q path, alpha=scale)
// mode 2: j<192 -> bf16 out_b (k), j>=192 -> fp32 out_f (v), both [b,h,n,d]
// mode 1: plain fp32 out_f[m*NJ+j] (final projection -> d_out)
// Tiling: 64x64 tile, BK=16, 256 threads, 4x4 micro-tile per thread.
// ---------------------------------------------------------------------------
__global__ __launch_bounds__(256) void proj_gemm(
    const float* __restrict__ X, const float* __restrict__ W,
    const float* __restrict__ bias,
    unsigned short* __restrict__ out_b, float* __restrict__ out_f,
    int mode, float alpha, int K, int NJ)
{
    __shared__ float Xs[16][64];
    __shared__ float Ws[16][64];

    const int t  = threadIdx.x;
    const int m0 = blockIdx.x * 64;
    const int j0 = blockIdx.y * 64;
    const int lr = t >> 2;          // 0..63 tile row
    const int lc = (t & 3) << 2;    // k offset 0,4,8,12
    const int tx = t & 15, ty = t >> 4;

    float acc[4][4] = {};
    const float* Xp = X + (size_t)(m0 + lr) * K + lc;
    const float* Wp = W + (size_t)(j0 + lr) * K + lc;

    for (int k0 = 0; k0 < K; k0 += 16) {
        float4 xv = *(const float4*)(Xp + k0);
        float4 wv = *(const float4*)(Wp + k0);
        __syncthreads();   // protect previous iteration's LDS reads
        Xs[lc+0][lr] = xv.x; Xs[lc+1][lr] = xv.y; Xs[lc+2][lr] = xv.z; Xs[lc+3][lr] = xv.w;
        Ws[lc+0][lr] = wv.x; Ws[lc+1][lr] = wv.y; Ws[lc+2][lr] = wv.z; Ws[lc+3][lr] = wv.w;
        __syncthreads();
        #pragma unroll
        for (int kk = 0; kk < 16; ++kk) {
            float4 a = *(const float4*)&Xs[kk][ty * 4];
            float4 b = *(const float4*)&Ws[kk][tx * 4];
            acc[0][0] += a.x*b.x; acc[0][1] += a.x*b.y; acc[0][2] += a.x*b.z; acc[0][3] += a.x*b.w;
            acc[1][0] += a.y*b.x; acc[1][1] += a.y*b.y; acc[1][2] += a.y*b.z; acc[1][3] += a.y*b.w;
            acc[2][0] += a.z*b.x; acc[2][1] += a.z*b.y; acc[2][2] += a.z*b.z; acc[2][3] += a.z*b.w;
            acc[3][0] += a.w*b.x; acc[3][1] += a.w*b.y; acc[3][2] += a.w*b.z; acc[3][3] += a.w*b.w;
        }
    }

    #pragma unroll
    for (int r = 0; r < 4; ++r) {
        int m  = m0 + ty * 4 + r;
        int bb = m / N_;
        int n  = m - bb * N_;
        #pragma unroll
        for (int c = 0; c < 4; ++c) {
            int j = j0 + tx * 4 + c;
            float val = (acc[r][c] + bias[j]) * alpha;
            if (mode == 1) {
                out_f[(size_t)m * NJ + j] = val;
            } else if (mode == 0) {
                int hh = j >> 5, dd = j & 31;
                out_b[(((size_t)bb * H_ + hh) * N_ + n) * D_ + dd] = f2b(val);
            } else { // mode 2: kv
                if (j < C_) {
                    int hh = j >> 5, dd = j & 31;
                    out_b[(((size_t)bb * H_ + hh) * N_ + n) * D_ + dd] = f2b(val);
                } else {
                    int jj = j - C_;
                    int hh = jj >> 5, dd = jj & 31;
                    out_f[(((size_t)bb * H_ + hh) * N_ + n) * D_ + dd] = val;
                }
            }
        }
    }
}

// ---------------------------------------------------------------------------
// rpb[h][n][m] = rpb_table[rpi[n][m]][h]    (2.8 MB, recomputed every launch)
// ---------------------------------------------------------------------------
__global__ __launch_bounds__(256) void rpb_gather(
    const float* __restrict__ table, const int* __restrict__ rpi,
    float* __restrict__ rpb)
{
    int idx = blockIdx.x * 256 + threadIdx.x;
    if (idx < NN_) {
        int id = rpi[idx];
        #pragma unroll
        for (int h = 0; h < H_; ++h)
            rpb[(size_t)h * NN_ + idx] = table[(size_t)id * H_ + h];
    }
}

// ---------------------------------------------------------------------------
// Attention: one block per (q-tile of 32 rows, head, batch-window).
// Phase 1: each lane owns key m (k row in 32 VGPRs, bf16->f32), loops the 32
//          query rows (q from LDS broadcast); rpb/mask reads coalesced in m.
// Phase 2: LDS softmax over S[32][345] (pad 345: stride%32=25, coprime).
// Phase 3: O = P @ V with V staged in 64-row LDS chunks; lane owns (row, 4 cols).
// ---------------------------------------------------------------------------
__global__ __launch_bounds__(256) void attn_kernel(
    const unsigned short* __restrict__ qb, const unsigned short* __restrict__ kb,
    const float* __restrict__ v, const float* __restrict__ rpb,
    const float* __restrict__ mask, float* __restrict__ ao)
{
    __shared__ float S[32][345];
    __shared__ float qs[32][32];
    __shared__ float Vc[64][32];
    __shared__ float red[32][8];
    __shared__ float rowmax[32];
    __shared__ float rowsum[32];

    const int t  = threadIdx.x;
    const int qt = blockIdx.x;           // 0..10
    const int h  = blockIdx.y;           // 0..5
    const int b  = blockIdx.z;           // 0..255
    const int bh = b * H_ + h;
    const int w  = b & (NW_ - 1);        // window index = b % 64
    const int r0 = qt * 32;

    // ---- load q tile (bf16 -> f32 LDS) ----
    {
        int row = t >> 3;                // 0..31
        int c4  = (t & 7) << 2;          // 0..28
        int n   = r0 + row; if (n > N_ - 1) n = N_ - 1;   // clamp tail tile
        const unsigned short* qp = qb + ((size_t)bh * N_ + n) * D_ + c4;
        uint2 u = *(const uint2*)qp;     // 4 bf16
        qs[row][c4+0] = b2f((unsigned short)(u.x & 0xffffu));
        qs[row][c4+1] = b2f((unsigned short)(u.x >> 16));
        qs[row][c4+2] = b2f((unsigned short)(u.y & 0xffffu));
        qs[row][c4+3] = b2f((unsigned short)(u.y >> 16));
    }
    __syncthreads();

    // ---- phase 1: S = q*scale . k + rpb + mask ----
    const float* rp = rpb  + (size_t)h * NN_;
    const float* mp = mask + (size_t)w * NN_;
    for (int pass = 0; pass < 2; ++pass) {
        int m = pass * 256 + t;
        bool act = (m < N_);
        int mcl = act ? m : N_ - 1;
        float kr[32];
        const unsigned short* kp = kb + ((size_t)bh * N_ + mcl) * D_;
        #pragma unroll
        for (int c8 = 0; c8 < 32; c8 += 8) {
            uint4 u = *(const uint4*)(kp + c8);   // 8 bf16
            kr[c8+0] = b2f((unsigned short)(u.x & 0xffffu)); kr[c8+1] = b2f((unsigned short)(u.x >> 16));
            kr[c8+2] = b2f((unsigned short)(u.y & 0xffffu)); kr[c8+3] = b2f((unsigned short)(u.y >> 16));
            kr[c8+4] = b2f((unsigned short)(u.z & 0xffffu)); kr[c8+5] = b2f((unsigned short)(u.z >> 16));
            kr[c8+6] = b2f((unsigned short)(u.w & 0xffffu)); kr[c8+7] = b2f((unsigned short)(u.w >> 16));
        }
        for (int i = 0; i < 32; ++i) {
            int n = r0 + i; if (n > N_ - 1) n = N_ - 1;
            float s = 0.f;
            #pragma unroll
            for (int c = 0; c < 32; ++c) s += qs[i][c] * kr[c];
            s += rp[(size_t)n * N_ + mcl] + mp[(size_t)n * N_ + mcl];
            if (act) S[i][m] = s;
        }
    }
    __syncthreads();

    // ---- phase 2: softmax (8 lanes per row) ----
    const int i2 = t >> 3, j2 = t & 7;
    {
        float mx = -3.0e38f;
        for (int m = j2; m < N_; m += 8) mx = fmaxf(mx, S[i2][m]);
        red[i2][j2] = mx;
    }
    __syncthreads();
    if (j2 == 0) {
        float r = red[i2][0];
        #pragma unroll
        for (int jj = 1; jj < 8; ++jj) r = fmaxf(r, red[i2][jj]);
        rowmax[i2] = r;
    }
    __syncthreads();
    {
        float rm = rowmax[i2];
        float sm = 0.f;
        for (int m = j2; m < N_; m += 8) {
            float e = __expf(S[i2][m] - rm);
            S[i2][m] = e;
            sm += e;
        }
        red[i2][j2] = sm;
    }
    __syncthreads();
    if (j2 == 0) {
        float r = 0.f;
        #pragma unroll
        for (int jj = 0; jj < 8; ++jj) r += red[i2][jj];
        rowsum[i2] = r;
    }
    // (rowsum visibility covered by first barrier of phase 3)

    // ---- phase 3: O = P @ V ----
    const int i3 = t >> 3;
    const int d4 = (t & 7) << 2;
    float4 acc = make_float4(0.f, 0.f, 0.f, 0.f);
    for (int mb = 0; mb < N_; mb += 64) {
        __syncthreads();   // protect previous Vc reads (and covers rowsum/S writes)
        for (int idx = t; idx < 512; idx += 256) {
            int row = idx >> 3, c4 = (idx & 7) << 2;
            if (mb + row < N_)
                *(float4*)&Vc[row][c4] =
                    *(const float4*)&v[((size_t)bh * N_ + mb + row) * D_ + c4];
        }
        __syncthreads();
        int len = N_ - mb; if (len > 64) len = 64;
        for (int mm = 0; mm < len; ++mm) {
            float p = S[i3][mb + mm];
            float4 vv = *(const float4*)&Vc[mm][d4];
            acc.x += p * vv.x; acc.y += p * vv.y;
            acc.z += p * vv.z; acc.w += p * vv.w;
        }
    }
    int n = r0 + i3;
    if (n < N_) {
        float inv = 1.0f / rowsum[i3];
        float4 o = make_float4(acc.x * inv, acc.y * inv, acc.z * inv, acc.w * inv);
        *(float4*)&ao[((size_t)b * N_ + n) * C_ + h * D_ + d4] = o;
    }
}

// ---------------------------------------------------------------------------
extern "C" void kernel_launch(void* const* d_in, const int* in_sizes, int n_in,
                              void* d_out, int out_size, void* d_ws, size_t ws_size,
                              hipStream_t stream)
{
    const float* x_q    = (const float*)d_in[0];
    const float* x_kv   = (const float*)d_in[1];
    const float* mask   = (const float*)d_in[2];
    const float* q_w    = (const float*)d_in[3];
    const float* q_b    = (const float*)d_in[4];
    const float* kv_w   = (const float*)d_in[5];
    const float* kv_b   = (const float*)d_in[6];
    const float* proj_w = (const float*)d_in[7];
    const float* proj_b = (const float*)d_in[8];
    const float* rpb_t  = (const float*)d_in[9];
    const int*   rpi    = (const int*)d_in[10];
    float* out = (float*)d_out;

    // workspace: q(bf16) 33.7MB | k(bf16) 33.7MB | v(f32) 67.4MB |
    //            ao(f32) 67.4MB | rpb(f32) 2.8MB   => ~205 MB total
    const size_t QKV = (size_t)B_ * H_ * N_ * D_;     // 16,859,136 elems
    char* ws = (char*)d_ws;
    unsigned short* qx = (unsigned short*)ws;
    unsigned short* kx = qx + QKV;
    float* vx  = (float*)(ws + QKV * 2 * sizeof(unsigned short));
    float* ao  = vx + QKV;
    float* rpb = ao + QKV;

    dim3 blk(256);
    // q projection (pre-scaled by d^-0.5), scatter to [b,h,n,d] bf16
    proj_gemm<<<dim3(M_/64, C_/64), blk, 0, stream>>>(
        x_q, q_w, q_b, qx, nullptr, 0, SCALE_, C_, C_);
    // kv projection: k -> bf16 [b,h,n,d], v -> f32 [b,h,n,d]
    proj_gemm<<<dim3(M_/64, (2*C_)/64), blk, 0, stream>>>(
        x_kv, kv_w, kv_b, kx, vx, 2, 1.0f, C_, 2*C_);
    // relative-position bias gather [H,N,N]
    rpb_gather<<<dim3((NN_ + 255)/256), blk, 0, stream>>>(rpb_t, rpi, rpb);
    // attention -> ao [b,n,c]
    attn_kernel<<<dim3((N_ + 31)/32, H_, B_), blk, 0, stream>>>(
        qx, kx, vx, rpb, mask, ao);
    // output projection -> d_out
    proj_gemm<<<dim3(M_/64, C_/64), blk, 0, stream>>>(
        ao, proj_w, proj_b, nullptr, out, 1, 1.0f, C_, C_);
}

// Round 2
// 885.424 us; speedup vs baseline: 16.5049x; 16.5049x over previous
//
#include <hip/hip_runtime.h>
#include <hip/hip_bf16.h>
#include <cstdint>

#define B_    256
#define N_    343
#define C_    192
#define H_    6
#define D_    32
#define NW_   64
#define M_    (B_*N_)           // 87808
#define NN_   (N_*N_)           // 117649
#define VTS_  352               // v-transposed global row stride (n padded to 22*16)
#define SCALE_ 0.17677669529663687f   // 32^-0.5

typedef unsigned short ushort_t;
typedef __attribute__((ext_vector_type(8))) short short8;   // 8 bf16 = one MFMA A/B frag
typedef __attribute__((ext_vector_type(4))) float f32x4;    // MFMA C/D frag

__device__ __forceinline__ float b2f(unsigned short u) {
    return __uint_as_float(((unsigned int)u) << 16);
}
__device__ __forceinline__ unsigned short f2b(float f) {
    unsigned int x = __float_as_uint(f);
    x += 0x7FFFu + ((x >> 16) & 1u);   // RNE
    return (unsigned short)(x >> 16);
}

// ---------------------------------------------------------------------------
// fp32 GEMM: out[m,j] = (sum_k X[m,k]*W[j,k] + bias[j]) * alpha
// mode 0: -> out_k bf16 at [b,h,n,d]                     (q path, alpha=scale)
// mode 2: j<192 -> out_k bf16 [b,h,n,d];  j>=192 -> out_vt bf16 [bh][d][n] stride VTS_
// mode 1: -> out_f fp32 [m,j]                            (final projection)
// ---------------------------------------------------------------------------
__global__ __launch_bounds__(256) void proj_gemm(
    const float* __restrict__ X, const float* __restrict__ W,
    const float* __restrict__ bias,
    ushort_t* __restrict__ out_k, ushort_t* __restrict__ out_vt,
    float* __restrict__ out_f,
    int mode, float alpha, int K, int NJ)
{
    __shared__ float Xs[16][64];
    __shared__ float Ws[16][64];

    const int t  = threadIdx.x;
    const int m0 = blockIdx.x * 64;
    const int j0 = blockIdx.y * 64;
    const int lr = t >> 2;
    const int lc = (t & 3) << 2;
    const int tx = t & 15, ty = t >> 4;

    float acc[4][4] = {};
    const float* Xp = X + (size_t)(m0 + lr) * K + lc;
    const float* Wp = W + (size_t)(j0 + lr) * K + lc;

    for (int k0 = 0; k0 < K; k0 += 16) {
        float4 xv = *(const float4*)(Xp + k0);
        float4 wv = *(const float4*)(Wp + k0);
        __syncthreads();
        Xs[lc+0][lr] = xv.x; Xs[lc+1][lr] = xv.y; Xs[lc+2][lr] = xv.z; Xs[lc+3][lr] = xv.w;
        Ws[lc+0][lr] = wv.x; Ws[lc+1][lr] = wv.y; Ws[lc+2][lr] = wv.z; Ws[lc+3][lr] = wv.w;
        __syncthreads();
        #pragma unroll
        for (int kk = 0; kk < 16; ++kk) {
            float4 a = *(const float4*)&Xs[kk][ty * 4];
            float4 b = *(const float4*)&Ws[kk][tx * 4];
            acc[0][0] += a.x*b.x; acc[0][1] += a.x*b.y; acc[0][2] += a.x*b.z; acc[0][3] += a.x*b.w;
            acc[1][0] += a.y*b.x; acc[1][1] += a.y*b.y; acc[1][2] += a.y*b.z; acc[1][3] += a.y*b.w;
            acc[2][0] += a.z*b.x; acc[2][1] += a.z*b.y; acc[2][2] += a.z*b.z; acc[2][3] += a.z*b.w;
            acc[3][0] += a.w*b.x; acc[3][1] += a.w*b.y; acc[3][2] += a.w*b.z; acc[3][3] += a.w*b.w;
        }
    }

    #pragma unroll
    for (int r = 0; r < 4; ++r) {
        int m  = m0 + ty * 4 + r;
        int bb = m / N_;
        int n  = m - bb * N_;
        #pragma unroll
        for (int c = 0; c < 4; ++c) {
            int j = j0 + tx * 4 + c;
            float val = (acc[r][c] + bias[j]) * alpha;
            if (mode == 1) {
                out_f[(size_t)m * NJ + j] = val;
            } else if (mode == 0) {
                int hh = j >> 5, dd = j & 31;
                out_k[(((size_t)bb * H_ + hh) * N_ + n) * D_ + dd] = f2b(val);
            } else { // mode 2
                if (j < C_) {
                    int hh = j >> 5, dd = j & 31;
                    out_k[(((size_t)bb * H_ + hh) * N_ + n) * D_ + dd] = f2b(val);
                } else {
                    int jj = j - C_;
                    int hh = jj >> 5, dd = jj & 31;
                    out_vt[((size_t)(bb * H_ + hh) * D_ + dd) * VTS_ + n] = f2b(val);
                }
            }
        }
    }
}

// rpbb[h][n][m] = bf16(rpb_table[rpi[n][m]][h])   (1.4 MB, L2-resident)
__global__ __launch_bounds__(256) void rpb_gather_b(
    const float* __restrict__ table, const int* __restrict__ rpi,
    ushort_t* __restrict__ rpbb)
{
    int idx = blockIdx.x * 256 + threadIdx.x;
    if (idx < NN_) {
        int id = rpi[idx];
        #pragma unroll
        for (int h = 0; h < H_; ++h)
            rpbb[(size_t)h * NN_ + idx] = f2b(table[(size_t)id * H_ + h]);
    }
}

// maskb = bf16(mask)  (0.0 / -100.0 both exact in bf16)
__global__ __launch_bounds__(256) void mask_to_b(
    const float* __restrict__ mask, ushort_t* __restrict__ maskb)
{
    int idx = blockIdx.x * 256 + threadIdx.x;     // over NW_*NN_/4
    if (idx < (NW_ * NN_) / 4) {
        float4 m4 = ((const float4*)mask)[idx];
        ushort4 u;
        u.x = f2b(m4.x); u.y = f2b(m4.y); u.z = f2b(m4.z); u.w = f2b(m4.w);
        ((ushort4*)maskb)[idx] = u;
    }
}

// zero vt pad columns n in [343,352) so PV pad contributes exactly 0
__global__ __launch_bounds__(256) void vt_pad(ushort_t* __restrict__ vtb)
{
    int bh = blockIdx.x;
    for (int i = threadIdx.x; i < D_ * (VTS_ - N_); i += 256) {  // 288
        int d = i / (VTS_ - N_), m = N_ + i % (VTS_ - N_);
        vtb[((size_t)bh * D_ + d) * VTS_ + m] = 0;
    }
}

// ---------------------------------------------------------------------------
// MFMA attention. Block = (64 q-rows, h, b); 4 waves, one 16-row strip each.
// QK^T: A=q frag (global), B=k frag (LDS, stride 40 -> 2-way banks, free).
// S in registers (C-layout: col=lane&15, row=quad*4+r). Softmax via in-lane
// reduce + 16-lane shfl_xor butterfly. P -> LDS (A-layout round-trip, pbuf
// aliases dead ks region after barrier). PV: B=V^T frags direct from global
// (consecutive blocks share bh -> L2 hits). LDS total 46 KB -> 3 blocks/CU.
// ---------------------------------------------------------------------------
__global__ __launch_bounds__(256, 2) void attn_mfma(
    const ushort_t* __restrict__ qb, const ushort_t* __restrict__ kb,
    const ushort_t* __restrict__ vtb, const ushort_t* __restrict__ rpbb,
    const ushort_t* __restrict__ maskb, float* __restrict__ ao)
{
    __shared__ ushort_t smem[23040];   // union: ks[352][40] (28160 B) / pbuf[4][16][360] (46080 B)
    ushort_t* ks = smem;
    ushort_t* pb = smem;

    const int t    = threadIdx.x;
    const int wv   = t >> 6;
    const int lane = t & 63;
    const int quad = lane >> 4;
    const int col  = lane & 15;
    const int qt = blockIdx.x, h = blockIdx.y, b = blockIdx.z;
    const int bh = b * H_ + h;
    const int w  = b & (NW_ - 1);
    const int r0 = qt * 64 + wv * 16;

    // ---- stage K tile: [row][d] bf16, row stride 40 elems ----
    const ushort_t* kbase = kb + (size_t)bh * (N_ * D_);
    for (int c = t; c < (N_ * D_) / 8; c += 256) {   // 1372 16B chunks
        int row = c >> 2, off = (c & 3) * 8;
        *(short8*)(ks + row * 40 + off) = *(const short8*)(kbase + c * 8);
    }

    // ---- q A-frag: lane holds q[r0 + (lane&15)][quad*8 .. +7] ----
    int qrow = r0 + col; if (qrow > N_ - 1) qrow = N_ - 1;   // clamp tail (dup rows, stores skipped)
    short8 qf = *(const short8*)(qb + ((size_t)bh * N_ + qrow) * D_ + quad * 8);

    __syncthreads();

    // ---- QK^T: 22 independent MFMAs, S kept in registers ----
    f32x4 sacc[22];
    #pragma unroll
    for (int kt = 0; kt < 22; ++kt) {
        short8 kf = *(const short8*)(ks + (kt * 16 + col) * 40 + quad * 8);
        sacc[kt] = __builtin_amdgcn_mfma_f32_16x16x32_bf16(qf, kf, (f32x4){0.f,0.f,0.f,0.f}, 0, 0, 0);
    }
    __syncthreads();   // all waves done with ks; pbuf may overwrite it

    // ---- add rpb + mask (bf16 global, L2/L3-resident); pad cols -> -inf ----
    const ushort_t* rp = rpbb + (size_t)h * NN_;
    const ushort_t* mp = maskb + (size_t)w * NN_;
    #pragma unroll
    for (int r = 0; r < 4; ++r) {
        int n = r0 + quad * 4 + r; if (n > N_ - 1) n = N_ - 1;
        const ushort_t* rpn = rp + (size_t)n * N_;
        const ushort_t* mpn = mp + (size_t)n * N_;
        #pragma unroll
        for (int kt = 0; kt < 22; ++kt) {
            int m = kt * 16 + col;
            if (m < N_) sacc[kt][r] += b2f(rpn[m]) + b2f(mpn[m]);
            else        sacc[kt][r] = -3.0e38f;    // replace (kills any LDS-junk NaN too)
        }
    }

    // ---- softmax: row-wise max/sum; rows of a strip live on one 16-lane group ----
    float rm[4], sm[4];
    #pragma unroll
    for (int r = 0; r < 4; ++r) {
        float v = sacc[0][r];
        #pragma unroll
        for (int kt = 1; kt < 22; ++kt) v = fmaxf(v, sacc[kt][r]);
        #pragma unroll
        for (int off = 1; off < 16; off <<= 1) v = fmaxf(v, __shfl_xor(v, off));
        rm[r] = v;
    }
    ushort_t* pbw = pb + wv * (16 * 360);
    #pragma unroll
    for (int r = 0; r < 4; ++r) {
        float s = 0.f;
        int rowoff = (quad * 4 + r) * 360;
        #pragma unroll
        for (int kt = 0; kt < 22; ++kt) {
            float e = __expf(sacc[kt][r] - rm[r]);   // pad cols: exp(-3e38-rm) = 0
            s += e;
            pbw[rowoff + kt * 16 + col] = f2b(e);
        }
        #pragma unroll
        for (int off = 1; off < 16; off <<= 1) s += __shfl_xor(s, off);
        sm[r] = s;
    }
    // (own-wave pbuf write->read: compiler orders via lgkmcnt, no barrier needed)

    // ---- PV: O[16x32] = P[16x352] @ V[352x32], V^T frags direct from global ----
    const ushort_t* vbase = vtb + (size_t)bh * (D_ * VTS_);
    const ushort_t* pra = pbw + col * 360 + quad * 8;   // A-frag: row = lane&15
    f32x4 oa = {0.f,0.f,0.f,0.f}, ob = {0.f,0.f,0.f,0.f};
    #pragma unroll
    for (int mt = 0; mt < 11; ++mt) {
        short8 pf = *(const short8*)(pra + mt * 32);
        short8 v0 = *(const short8*)(vbase + (size_t)col * VTS_ + mt * 32 + quad * 8);
        short8 v1 = *(const short8*)(vbase + (size_t)(16 + col) * VTS_ + mt * 32 + quad * 8);
        oa = __builtin_amdgcn_mfma_f32_16x16x32_bf16(pf, v0, oa, 0, 0, 0);
        ob = __builtin_amdgcn_mfma_f32_16x16x32_bf16(pf, v1, ob, 0, 0, 0);
    }

    // ---- normalize + store (C-layout: row=quad*4+r, col=lane&15) ----
    #pragma unroll
    for (int r = 0; r < 4; ++r) {
        int n = r0 + quad * 4 + r;
        if (n < N_) {
            float inv = 1.0f / sm[r];
            float* op = ao + ((size_t)b * N_ + n) * C_ + h * D_;
            op[col]      = oa[r] * inv;
            op[16 + col] = ob[r] * inv;
        }
    }
}

// ---------------------------------------------------------------------------
extern "C" void kernel_launch(void* const* d_in, const int* in_sizes, int n_in,
                              void* d_out, int out_size, void* d_ws, size_t ws_size,
                              hipStream_t stream)
{
    const float* x_q    = (const float*)d_in[0];
    const float* x_kv   = (const float*)d_in[1];
    const float* mask   = (const float*)d_in[2];
    const float* q_w    = (const float*)d_in[3];
    const float* q_b    = (const float*)d_in[4];
    const float* kv_w   = (const float*)d_in[5];
    const float* kv_b   = (const float*)d_in[6];
    const float* proj_w = (const float*)d_in[7];
    const float* proj_b = (const float*)d_in[8];
    const float* rpb_t  = (const float*)d_in[9];
    const int*   rpi    = (const int*)d_in[10];
    float* out = (float*)d_out;

    // ws: ao f32 67.4MB | q bf16 33.7 | k bf16 33.7 | vt bf16 34.6 | rpbb 1.4 | maskb 15.1  = ~186MB
    const size_t QKV = (size_t)B_ * H_ * N_ * D_;        // 16,859,136
    float*    ao    = (float*)d_ws;
    ushort_t* qx    = (ushort_t*)(ao + (size_t)M_ * C_);
    ushort_t* kx    = qx + QKV;
    ushort_t* vtb   = kx + QKV;
    ushort_t* rpbb  = vtb + (size_t)B_ * H_ * D_ * VTS_;
    ushort_t* maskb = rpbb + 705896;                     // 6*NN_ padded to x8 for alignment

    proj_gemm<<<dim3(M_/64, C_/64), 256, 0, stream>>>(
        x_q, q_w, q_b, qx, nullptr, nullptr, 0, SCALE_, C_, C_);
    proj_gemm<<<dim3(M_/64, (2*C_)/64), 256, 0, stream>>>(
        x_kv, kv_w, kv_b, kx, vtb, nullptr, 2, 1.0f, C_, 2*C_);
    rpb_gather_b<<<(NN_ + 255)/256, 256, 0, stream>>>(rpb_t, rpi, rpbb);
    mask_to_b<<<(NW_*NN_/4 + 255)/256, 256, 0, stream>>>(mask, maskb);
    vt_pad<<<B_*H_, 256, 0, stream>>>(vtb);
    attn_mfma<<<dim3(6, H_, B_), 256, 0, stream>>>(qx, kx, vtb, rpbb, maskb, ao);
    proj_gemm<<<dim3(M_/64, C_/64), 256, 0, stream>>>(
        ao, proj_w, proj_b, nullptr, nullptr, out, 1, 1.0f, C_, C_);
}

// Round 3
// 815.146 us; speedup vs baseline: 17.9279x; 1.0862x over previous
//
#include <hip/hip_runtime.h>
#include <hip/hip_bf16.h>
#include <cstdint>

#define B_    256
#define N_    343
#define C_    192
#define H_    6
#define D_    32
#define NW_   64
#define M_    (B_*N_)           // 87808 = 1372*64
#define NN_   (N_*N_)           // 117649
#define VTS_  352               // v-transposed row stride (n padded to 22*16)
#define SCALE_ 0.17677669529663687f   // 32^-0.5

typedef unsigned short ushort_t;
typedef __attribute__((ext_vector_type(8))) short short8;   // 8 bf16 = MFMA A/B frag
typedef __attribute__((ext_vector_type(4))) float f32x4;    // MFMA C/D frag

__device__ __forceinline__ float b2f(unsigned short u) {
    return __uint_as_float(((unsigned int)u) << 16);
}
__device__ __forceinline__ unsigned short f2b(float f) {
    unsigned int x = __float_as_uint(f);
    x += 0x7FFFu + ((x >> 16) & 1u);   // RNE
    return (unsigned short)(x >> 16);
}

// ---------------------------------------------------------------------------
// MFMA GEMM: out[m,j] = (sum_k X[m,k]*W[j,k] + bias[j]) * alpha,  K=192.
// W fp32 [NJ][192] staged to LDS as bf16 with +8 pad (stride 200 elems:
// unpadded 192*2B=384B = 0 mod 128B -> 16-way bank conflict; 200 -> 2-way free).
// X read as fp32 (x_bf16=0, inline cvt) or bf16 (x_bf16=1). 4 waves, 16-row
// strips, 12 col-tiles x 6 k-tiles = 72 MFMAs/wave, single barrier.
// mode 0: -> o16 bf16 [bh][n][d] (q, alpha=SCALE)
// mode 2: jg<192 -> o16 bf16 [bh][n][d] (k); jg>=192 -> ovt bf16 [bh][d][n] stride VTS_
// mode 1: -> o32 fp32 [m][192] (final projection)
// ---------------------------------------------------------------------------
__global__ __launch_bounds__(256) void gemm_xw(
    const void* __restrict__ Xv, const float* __restrict__ W,
    const float* __restrict__ bias,
    ushort_t* __restrict__ o16, ushort_t* __restrict__ ovt,
    float* __restrict__ o32, int mode, int x_bf16, float alpha)
{
    __shared__ ushort_t wls[192 * 200];   // 76800 B

    const int t    = threadIdx.x;
    const int wv   = t >> 6;
    const int lane = t & 63;
    const int quad = lane >> 4;
    const int col  = lane & 15;
    const int m0   = blockIdx.x * 64;
    const int jb   = blockIdx.y;

    // stage W jb-slice fp32 -> bf16 LDS
    const float* Wp = W + (size_t)jb * 192 * 192;
    for (int c = t; c < 9216; c += 256) {           // 9216 float4 chunks
        int row = c / 48, o4 = c % 48;
        float4 w4 = ((const float4*)Wp)[(size_t)row * 48 + o4];
        ushort4 u;
        u.x = f2b(w4.x); u.y = f2b(w4.y); u.z = f2b(w4.z); u.w = f2b(w4.w);
        *(ushort4*)(wls + row * 200 + o4 * 4) = u;
    }

    // A-frags: lane holds X[m0+wv*16+col][kt*32+quad*8 .. +7] for kt=0..5
    const int arow = m0 + wv * 16 + col;
    short8 af[6];
    if (x_bf16) {
        const ushort_t* Xb = (const ushort_t*)Xv + (size_t)arow * 192;
        #pragma unroll
        for (int kt = 0; kt < 6; ++kt)
            af[kt] = *(const short8*)(Xb + kt * 32 + quad * 8);
    } else {
        const float* Xf = (const float*)Xv + (size_t)arow * 192;
        #pragma unroll
        for (int kt = 0; kt < 6; ++kt) {
            float4 a0 = *(const float4*)(Xf + kt * 32 + quad * 8);
            float4 a1 = *(const float4*)(Xf + kt * 32 + quad * 8 + 4);
            short8 f;
            f[0] = (short)f2b(a0.x); f[1] = (short)f2b(a0.y);
            f[2] = (short)f2b(a0.z); f[3] = (short)f2b(a0.w);
            f[4] = (short)f2b(a1.x); f[5] = (short)f2b(a1.y);
            f[6] = (short)f2b(a1.z); f[7] = (short)f2b(a1.w);
            af[kt] = f;
        }
    }
    __syncthreads();

    f32x4 acc[12] = {};
    #pragma unroll
    for (int kt = 0; kt < 6; ++kt)
        #pragma unroll
        for (int ct = 0; ct < 12; ++ct) {
            short8 bf = *(const short8*)(wls + (ct * 16 + col) * 200 + kt * 32 + quad * 8);
            acc[ct] = __builtin_amdgcn_mfma_f32_16x16x32_bf16(af[kt], bf, acc[ct], 0, 0, 0);
        }

    // epilogue: C-layout row = quad*4+r, col-tile ct
    #pragma unroll
    for (int ct = 0; ct < 12; ++ct) {
        int jl = ct * 16 + col;
        int jg = jb * 192 + jl;
        float bv = bias[jg];
        #pragma unroll
        for (int r = 0; r < 4; ++r) {
            int m  = m0 + wv * 16 + quad * 4 + r;
            int bb = m / N_;
            int n  = m - bb * N_;
            float val = (acc[ct][r] + bv) * alpha;
            if (mode == 1) {
                o32[(size_t)m * 192 + jl] = val;
            } else if (mode == 0) {
                int hh = jl >> 5, dd = jl & 31;
                o16[(((size_t)bb * H_ + hh) * N_ + n) * D_ + dd] = f2b(val);
            } else { // mode 2
                if (jg < C_) {
                    int hh = jg >> 5, dd = jg & 31;
                    o16[(((size_t)bb * H_ + hh) * N_ + n) * D_ + dd] = f2b(val);
                } else {
                    int jj = jg - C_;
                    int hh = jj >> 5, dd = jj & 31;
                    ovt[(((size_t)bb * H_ + hh) * D_ + dd) * VTS_ + n] = f2b(val);
                }
            }
        }
    }
}

// rpbb[h][n][m] = bf16(rpb_table[rpi[n][m]][h])   (1.4 MB, L2-resident)
__global__ __launch_bounds__(256) void rpb_gather_b(
    const float* __restrict__ table, const int* __restrict__ rpi,
    ushort_t* __restrict__ rpbb)
{
    int idx = blockIdx.x * 256 + threadIdx.x;
    if (idx < NN_) {
        int id = rpi[idx];
        #pragma unroll
        for (int h = 0; h < H_; ++h)
            rpbb[(size_t)h * NN_ + idx] = f2b(table[(size_t)id * H_ + h]);
    }
}

// mbits[w][n][12 dwords]: bit m set iff mask[w][n][m] == 0 (unmasked).
// One wave per (w,n,seg): 64 coalesced reads -> __ballot -> 2 dword writes.
__global__ __launch_bounds__(256) void mask_bits(
    const float* __restrict__ mask, unsigned int* __restrict__ mbits)
{
    int gw   = (blockIdx.x * 256 + threadIdx.x) >> 6;   // 0 .. 64*343*6-1
    int lane = threadIdx.x & 63;
    int seg = gw % 6; int rem = gw / 6;
    int n = rem % N_; int w = rem / N_;
    int m = seg * 64 + lane;
    float v = (m < N_) ? mask[((size_t)w * N_ + n) * N_ + m] : -100.f;
    unsigned long long bm = __ballot(v > -50.f);
    if (lane < 2)
        mbits[((size_t)w * N_ + n) * 12 + seg * 2 + lane] = (unsigned int)(bm >> (lane * 32));
}

// zero vt pad columns n in [343,352)
__global__ __launch_bounds__(256) void vt_pad(ushort_t* __restrict__ vtb)
{
    int bh = blockIdx.x;
    for (int i = threadIdx.x; i < D_ * (VTS_ - N_); i += 256) {
        int d = i / (VTS_ - N_), m = N_ + i % (VTS_ - N_);
        vtb[((size_t)bh * D_ + d) * VTS_ + m] = 0;
    }
}

// ---------------------------------------------------------------------------
// MFMA attention. Block = (64 q-rows, h, b); 4 waves, one 16-row strip each.
// Bias path: rpb additive bf16 (1.4 MB L2-hot, 88 scalar loads/lane) + 1-bit
// mask (3 uint4 vector loads per row). Masked / pad cols -> -3e38 -> exp = 0.
// P -> LDS A-layout round-trip (pbuf aliases ks after barrier). PV with V^T
// frags direct from global (bh slice L2-shared). ao written bf16.
// ---------------------------------------------------------------------------
__global__ __launch_bounds__(256, 2) void attn_mfma(
    const ushort_t* __restrict__ qb, const ushort_t* __restrict__ kb,
    const ushort_t* __restrict__ vtb, const ushort_t* __restrict__ rpbb,
    const unsigned int* __restrict__ mbits, ushort_t* __restrict__ aob)
{
    __shared__ ushort_t smem[23040];   // union: ks[352][40] (28160 B) / pbuf[4][16][360] (46080 B)
    ushort_t* ks = smem;
    ushort_t* pb = smem;

    const int t    = threadIdx.x;
    const int wv   = t >> 6;
    const int lane = t & 63;
    const int quad = lane >> 4;
    const int col  = lane & 15;
    const int qt = blockIdx.x, h = blockIdx.y, b = blockIdx.z;
    const int bh = b * H_ + h;
    const int w  = b & (NW_ - 1);
    const int r0 = qt * 64 + wv * 16;

    // stage K tile [row][d], row stride 40 elems
    const ushort_t* kbase = kb + (size_t)bh * (N_ * D_);
    for (int c = t; c < (N_ * D_) / 8; c += 256) {
        int row = c >> 2, off = (c & 3) * 8;
        *(short8*)(ks + row * 40 + off) = *(const short8*)(kbase + c * 8);
    }

    // q A-frag
    int qrow = r0 + col; if (qrow > N_ - 1) qrow = N_ - 1;
    short8 qf = *(const short8*)(qb + ((size_t)bh * N_ + qrow) * D_ + quad * 8);

    __syncthreads();

    // QK^T: 22 MFMAs, S in registers (C-layout)
    f32x4 sacc[22];
    #pragma unroll
    for (int kt = 0; kt < 22; ++kt) {
        short8 kf = *(const short8*)(ks + (kt * 16 + col) * 40 + quad * 8);
        sacc[kt] = __builtin_amdgcn_mfma_f32_16x16x32_bf16(qf, kf, (f32x4){0.f,0.f,0.f,0.f}, 0, 0, 0);
    }
    __syncthreads();   // ks dead; pbuf may overwrite

    // rpb add + bitmask apply; pad/masked -> -3e38 (also kills ks-junk NaN)
    const ushort_t* rp = rpbb + (size_t)h * NN_;
    #pragma unroll
    for (int r = 0; r < 4; ++r) {
        int n = r0 + quad * 4 + r; if (n > N_ - 1) n = N_ - 1;
        const uint4* mrow = (const uint4*)(mbits + ((size_t)w * N_ + n) * 12);
        uint4 c0 = mrow[0], c1 = mrow[1], c2 = mrow[2];
        unsigned int dw[12] = {c0.x,c0.y,c0.z,c0.w, c1.x,c1.y,c1.z,c1.w, c2.x,c2.y,c2.z,c2.w};
        const ushort_t* rpn = rp + (size_t)n * N_;
        #pragma unroll
        for (int kt = 0; kt < 22; ++kt) {
            int m  = kt * 16 + col;
            int mc = m < N_ ? m : N_ - 1;
            float rb = b2f(rpn[mc]);
            unsigned int bit = (dw[kt >> 1] >> (((kt & 1) << 4) + col)) & 1u;
            sacc[kt][r] = (m < N_ && bit) ? (sacc[kt][r] + rb) : -3.0e38f;
        }
    }

    // softmax (rows of a strip live on one 16-lane group)
    float rm[4], sm[4];
    #pragma unroll
    for (int r = 0; r < 4; ++r) {
        float v = sacc[0][r];
        #pragma unroll
        for (int kt = 1; kt < 22; ++kt) v = fmaxf(v, sacc[kt][r]);
        #pragma unroll
        for (int off = 1; off < 16; off <<= 1) v = fmaxf(v, __shfl_xor(v, off));
        rm[r] = v;
    }
    ushort_t* pbw = pb + wv * (16 * 360);
    #pragma unroll
    for (int r = 0; r < 4; ++r) {
        float s = 0.f;
        int rowoff = (quad * 4 + r) * 360;
        #pragma unroll
        for (int kt = 0; kt < 22; ++kt) {
            float e = __expf(sacc[kt][r] - rm[r]);
            s += e;
            pbw[rowoff + kt * 16 + col] = f2b(e);
        }
        #pragma unroll
        for (int off = 1; off < 16; off <<= 1) s += __shfl_xor(s, off);
        sm[r] = s;
    }

    // PV: O[16x32] = P[16x352] @ V[352x32]
    const ushort_t* vbase = vtb + (size_t)bh * (D_ * VTS_);
    const ushort_t* pra = pbw + col * 360 + quad * 8;
    f32x4 oa = {0.f,0.f,0.f,0.f}, ob = {0.f,0.f,0.f,0.f};
    #pragma unroll
    for (int mt = 0; mt < 11; ++mt) {
        short8 pf = *(const short8*)(pra + mt * 32);
        short8 v0 = *(const short8*)(vbase + (size_t)col * VTS_ + mt * 32 + quad * 8);
        short8 v1 = *(const short8*)(vbase + (size_t)(16 + col) * VTS_ + mt * 32 + quad * 8);
        oa = __builtin_amdgcn_mfma_f32_16x16x32_bf16(pf, v0, oa, 0, 0, 0);
        ob = __builtin_amdgcn_mfma_f32_16x16x32_bf16(pf, v1, ob, 0, 0, 0);
    }

    // normalize + store bf16
    #pragma unroll
    for (int r = 0; r < 4; ++r) {
        int n = r0 + quad * 4 + r;
        if (n < N_) {
            float inv = 1.0f / sm[r];
            ushort_t* op = aob + ((size_t)b * N_ + n) * C_ + h * D_;
            op[col]      = f2b(oa[r] * inv);
            op[16 + col] = f2b(ob[r] * inv);
        }
    }
}

// ---------------------------------------------------------------------------
extern "C" void kernel_launch(void* const* d_in, const int* in_sizes, int n_in,
                              void* d_out, int out_size, void* d_ws, size_t ws_size,
                              hipStream_t stream)
{
    const float* x_q    = (const float*)d_in[0];
    const float* x_kv   = (const float*)d_in[1];
    const float* mask   = (const float*)d_in[2];
    const float* q_w    = (const float*)d_in[3];
    const float* q_b    = (const float*)d_in[4];
    const float* kv_w   = (const float*)d_in[5];
    const float* kv_b   = (const float*)d_in[6];
    const float* proj_w = (const float*)d_in[7];
    const float* proj_b = (const float*)d_in[8];
    const float* rpb_t  = (const float*)d_in[9];
    const int*   rpi    = (const int*)d_in[10];
    float* out = (float*)d_out;

    // ws: qx 33.7 | kx 33.7 | vtb 34.6 | aob 33.7 | rpbb 1.4 | mbits 1.05  = ~138 MB
    const size_t QKV  = (size_t)B_ * H_ * N_ * D_;       // 16,859,136
    const size_t QKV2 = (size_t)B_ * H_ * D_ * VTS_;     // 17,301,504
    char* ws = (char*)d_ws;
    ushort_t* qx   = (ushort_t*)ws;
    ushort_t* kx   = qx + QKV;
    ushort_t* vtb  = kx + QKV;
    ushort_t* aob  = vtb + QKV2;
    ushort_t* rpbb = aob + QKV;
    unsigned int* mbits = (unsigned int*)(rpbb + 705904);  // 6*NN_ padded to x8

    rpb_gather_b<<<(NN_ + 255)/256, 256, 0, stream>>>(rpb_t, rpi, rpbb);
    mask_bits<<<(NW_ * N_ * 6) / 4, 256, 0, stream>>>(mask, mbits);
    vt_pad<<<B_ * H_, 256, 0, stream>>>(vtb);
    // q projection (alpha=scale) -> bf16 [bh][n][d]
    gemm_xw<<<dim3(M_/64, 1), 256, 0, stream>>>(
        x_q, q_w, q_b, qx, nullptr, nullptr, 0, 0, SCALE_);
    // kv projection: k -> bf16 [bh][n][d], v -> bf16 [bh][d][n]
    gemm_xw<<<dim3(M_/64, 2), 256, 0, stream>>>(
        x_kv, kv_w, kv_b, kx, vtb, nullptr, 2, 0, 1.0f);
    // attention -> aob bf16 [b][n][c]
    attn_mfma<<<dim3(6, H_, B_), 256, 0, stream>>>(qx, kx, vtb, rpbb, mbits, aob);
    // output projection -> d_out fp32
    gemm_xw<<<dim3(M_/64, 1), 256, 0, stream>>>(
        aob, proj_w, proj_b, nullptr, nullptr, out, 1, 1, 1.0f);
}

// Round 4
// 480.558 us; speedup vs baseline: 30.4101x; 1.6962x over previous
//
#include <hip/hip_runtime.h>
#include <hip/hip_bf16.h>
#include <cstdint>

#define B_    256
#define N_    343
#define C_    192
#define H_    6
#define D_    32
#define NW_   64
#define M_    (B_*N_)           // 87808 = 686*128
#define NN_   (N_*N_)           // 117649
#define VTS_  352               // v-transposed row stride (m padded to 22*16)
#define RPS_  344               // rpbb row stride (elems): rows 8B-aligned
#define PBS_  376               // pbuf row stride (elems): 752B -> 2-way banks (free), 16B-aligned
#define SCALE_ 0.17677669529663687f   // 32^-0.5

typedef unsigned short ushort_t;
typedef __attribute__((ext_vector_type(8))) short short8;   // 8 bf16 = MFMA A/B frag
typedef __attribute__((ext_vector_type(4))) float f32x4;    // MFMA C/D frag

__device__ __forceinline__ float b2f(unsigned int u) {
    return __uint_as_float(u << 16);
}
__device__ __forceinline__ unsigned int f2b(float f) {
    unsigned int x = __float_as_uint(f);
    x += 0x7FFFu + ((x >> 16) & 1u);   // RNE
    return x >> 16;
}

// ---------------------------------------------------------------------------
// Convert all weight matrices fp32 -> bf16 once: wb = [q_w | k_w | v_w | proj_w]
// each 192x192 natural row-major.
// ---------------------------------------------------------------------------
__global__ __launch_bounds__(256) void wcvt(
    const float* __restrict__ qw, const float* __restrict__ kvw,
    const float* __restrict__ pw, ushort_t* __restrict__ wb)
{
    int i = blockIdx.x * 256 + threadIdx.x;   // float4 chunk index, 36864 total
    if (i >= 36864) return;
    float4 v;
    if (i < 9216)       v = ((const float4*)qw)[i];
    else if (i < 27648) v = ((const float4*)kvw)[i - 9216];   // k then v slices of kv_w
    else                v = ((const float4*)pw)[i - 27648];
    ushort4 u;
    u.x = (ushort_t)f2b(v.x); u.y = (ushort_t)f2b(v.y);
    u.z = (ushort_t)f2b(v.z); u.w = (ushort_t)f2b(v.w);
    ((ushort4*)wb)[i] = u;
}

// ---------------------------------------------------------------------------
// QKV projection, bf16 MFMA. Grid (686, 3): jsel 0=q,1=k,2=v. Block does two
// 64-row m-tiles sharing one LDS W-stage; one ds_read_b128 feeds 2 MFMAs.
// jsel 0/1: OUT^T orientation (lane=token, regs=j) -> 8B packed stores.
// jsel 2:   normal orientation (regs=token, lane=j) -> vtb [bh][d][n] stores.
// ---------------------------------------------------------------------------
__global__ __launch_bounds__(256, 2) void gemm_qkv(
    const float* __restrict__ xq, const float* __restrict__ xkv,
    const ushort_t* __restrict__ wb,
    const float* __restrict__ qbias, const float* __restrict__ kvbias,
    ushort_t* __restrict__ qx, ushort_t* __restrict__ kx,
    ushort_t* __restrict__ vtb)
{
    __shared__ ushort_t wls[192 * 200];   // 76800 B, stride 200 -> 2-way banks (free)

    const int t = threadIdx.x, wv = t >> 6, lane = t & 63;
    const int quad = lane >> 4, col = lane & 15;
    const int jsel = blockIdx.y;
    const int m0 = blockIdx.x * 128;
    const ushort_t* W = wb + (size_t)jsel * 36864;
    const float* Xf = (jsel == 0) ? xq : xkv;
    const float* bias = (jsel == 0) ? qbias : (jsel == 1 ? kvbias : kvbias + 192);
    const float alpha = (jsel == 0) ? SCALE_ : 1.0f;

    for (int c = t; c < 4608; c += 256) {          // 4608 16B chunks of W
        int row = c / 24, off = (c % 24) * 8;
        *(short8*)(wls + row * 200 + off) = *(const short8*)(W + row * 192 + off);
    }

    // A(x) frags for both m-tiles (fp32 -> bf16 inline)
    short8 xf[2][6];
    #pragma unroll
    for (int ti = 0; ti < 2; ++ti) {
        const float* xp = Xf + (size_t)(m0 + ti * 64 + wv * 16 + col) * 192;
        #pragma unroll
        for (int kt = 0; kt < 6; ++kt) {
            float4 a0 = *(const float4*)(xp + kt * 32 + quad * 8);
            float4 a1 = *(const float4*)(xp + kt * 32 + quad * 8 + 4);
            short8 f;
            f[0] = (short)f2b(a0.x); f[1] = (short)f2b(a0.y);
            f[2] = (short)f2b(a0.z); f[3] = (short)f2b(a0.w);
            f[4] = (short)f2b(a1.x); f[5] = (short)f2b(a1.y);
            f[6] = (short)f2b(a1.z); f[7] = (short)f2b(a1.w);
            xf[ti][kt] = f;
        }
    }
    __syncthreads();

    f32x4 acc[2][12] = {};
    if (jsel < 2) {
        #pragma unroll
        for (int kt = 0; kt < 6; ++kt)
            #pragma unroll
            for (int ct = 0; ct < 12; ++ct) {
                short8 wf = *(const short8*)(wls + (ct * 16 + col) * 200 + kt * 32 + quad * 8);
                acc[0][ct] = __builtin_amdgcn_mfma_f32_16x16x32_bf16(wf, xf[0][kt], acc[0][ct], 0, 0, 0);
                acc[1][ct] = __builtin_amdgcn_mfma_f32_16x16x32_bf16(wf, xf[1][kt], acc[1][ct], 0, 0, 0);
            }
        // epilogue ^T: D[row=j-sub][col=token]; pack 4 consecutive d -> 8B store
        ushort_t* o16 = (jsel == 0) ? qx : kx;
        #pragma unroll
        for (int ti = 0; ti < 2; ++ti) {
            int m = m0 + ti * 64 + wv * 16 + col;
            int bb = m / N_, nn = m - bb * N_;
            #pragma unroll
            for (int ct = 0; ct < 12; ++ct) {
                float4 bv = *(const float4*)(bias + ct * 16 + quad * 4);
                int hh = ct >> 1;
                int dbase = (ct & 1) * 16 + quad * 4;
                float v0 = (acc[ti][ct][0] + bv.x) * alpha;
                float v1 = (acc[ti][ct][1] + bv.y) * alpha;
                float v2 = (acc[ti][ct][2] + bv.z) * alpha;
                float v3 = (acc[ti][ct][3] + bv.w) * alpha;
                uint2 pk;
                pk.x = f2b(v0) | (f2b(v1) << 16);
                pk.y = f2b(v2) | (f2b(v3) << 16);
                *(uint2*)(o16 + (((size_t)bb * H_ + hh) * N_ + nn) * D_ + dbase) = pk;
            }
        }
    } else {
        #pragma unroll
        for (int kt = 0; kt < 6; ++kt)
            #pragma unroll
            for (int ct = 0; ct < 12; ++ct) {
                short8 wf = *(const short8*)(wls + (ct * 16 + col) * 200 + kt * 32 + quad * 8);
                acc[0][ct] = __builtin_amdgcn_mfma_f32_16x16x32_bf16(xf[0][kt], wf, acc[0][ct], 0, 0, 0);
                acc[1][ct] = __builtin_amdgcn_mfma_f32_16x16x32_bf16(xf[1][kt], wf, acc[1][ct], 0, 0, 0);
            }
        // epilogue normal: D[row=token][col=j]; vtb[bh][d][n], window-straddle safe
        #pragma unroll
        for (int ti = 0; ti < 2; ++ti) {
            int mbase = m0 + ti * 64 + wv * 16 + quad * 4;
            int bb = mbase / N_, nn = mbase - bb * N_;
            #pragma unroll
            for (int ct = 0; ct < 12; ++ct) {
                int j = ct * 16 + col;
                int hh = j >> 5, dd = j & 31;
                float bs = bias[j];
                size_t base = (((size_t)bb * H_ + hh) * D_ + dd) * VTS_;
                #pragma unroll
                for (int r = 0; r < 4; ++r) {
                    float val = acc[ti][ct][r] + bs;
                    int nr = nn + r;
                    size_t badj = base;
                    if (nr >= N_) { nr -= N_; badj += (size_t)H_ * D_ * VTS_; }
                    vtb[badj + nr] = (ushort_t)f2b(val);
                }
            }
        }
    }
}

// ---------------------------------------------------------------------------
// Output projection: aob bf16 [m][192] @ proj_w^T + bias -> fp32 out [m][192].
// Same structure, ^T orientation -> float4 stores.
// ---------------------------------------------------------------------------
__global__ __launch_bounds__(256, 2) void gemm_out(
    const ushort_t* __restrict__ aob, const ushort_t* __restrict__ wb,
    const float* __restrict__ pbias, float* __restrict__ out)
{
    __shared__ ushort_t wls[192 * 200];

    const int t = threadIdx.x, wv = t >> 6, lane = t & 63;
    const int quad = lane >> 4, col = lane & 15;
    const int m0 = blockIdx.x * 128;
    const ushort_t* W = wb + (size_t)3 * 36864;

    for (int c = t; c < 4608; c += 256) {
        int row = c / 24, off = (c % 24) * 8;
        *(short8*)(wls + row * 200 + off) = *(const short8*)(W + row * 192 + off);
    }

    short8 xf[2][6];
    #pragma unroll
    for (int ti = 0; ti < 2; ++ti) {
        const ushort_t* xp = aob + (size_t)(m0 + ti * 64 + wv * 16 + col) * 192;
        #pragma unroll
        for (int kt = 0; kt < 6; ++kt)
            xf[ti][kt] = *(const short8*)(xp + kt * 32 + quad * 8);
    }
    __syncthreads();

    f32x4 acc[2][12] = {};
    #pragma unroll
    for (int kt = 0; kt < 6; ++kt)
        #pragma unroll
        for (int ct = 0; ct < 12; ++ct) {
            short8 wf = *(const short8*)(wls + (ct * 16 + col) * 200 + kt * 32 + quad * 8);
            acc[0][ct] = __builtin_amdgcn_mfma_f32_16x16x32_bf16(wf, xf[0][kt], acc[0][ct], 0, 0, 0);
            acc[1][ct] = __builtin_amdgcn_mfma_f32_16x16x32_bf16(wf, xf[1][kt], acc[1][ct], 0, 0, 0);
        }

    #pragma unroll
    for (int ti = 0; ti < 2; ++ti) {
        int m = m0 + ti * 64 + wv * 16 + col;
        #pragma unroll
        for (int ct = 0; ct < 12; ++ct) {
            float4 bv = *(const float4*)(pbias + ct * 16 + quad * 4);
            float4 vo;
            vo.x = acc[ti][ct][0] + bv.x; vo.y = acc[ti][ct][1] + bv.y;
            vo.z = acc[ti][ct][2] + bv.z; vo.w = acc[ti][ct][3] + bv.w;
            *(float4*)(out + (size_t)m * 192 + ct * 16 + quad * 4) = vo;
        }
    }
}

// rpbb[h][n][m] with row stride RPS_=344 (8B-aligned rows); pad cols garbage (masked)
__global__ __launch_bounds__(256) void rpb_gather_b(
    const float* __restrict__ table, const int* __restrict__ rpi,
    ushort_t* __restrict__ rpbb)
{
    int n = blockIdx.x;
    for (int m = threadIdx.x; m < N_; m += 256) {
        int id = rpi[n * N_ + m];
        #pragma unroll
        for (int h = 0; h < H_; ++h)
            rpbb[(size_t)h * (N_ * RPS_) + (size_t)n * RPS_ + m] =
                (ushort_t)f2b(table[(size_t)id * H_ + h]);
    }
}

// mbits[w][n][12 dwords]: bit m set iff mask[w][n][m] == 0 (unmasked)
__global__ __launch_bounds__(256) void mask_bits(
    const float* __restrict__ mask, unsigned int* __restrict__ mbits)
{
    int gw   = (blockIdx.x * 256 + threadIdx.x) >> 6;
    int lane = threadIdx.x & 63;
    int seg = gw % 6; int rem = gw / 6;
    int n = rem % N_; int w = rem / N_;
    int m = seg * 64 + lane;
    float v = (m < N_) ? mask[((size_t)w * N_ + n) * N_ + m] : -100.f;
    unsigned long long bm = __ballot(v > -50.f);
    if (lane < 2)
        mbits[((size_t)w * N_ + n) * 12 + seg * 2 + lane] = (unsigned int)(bm >> (lane * 32));
}

// zero vtb pad columns n in [343,352)
__global__ __launch_bounds__(256) void vt_pad(ushort_t* __restrict__ vtb)
{
    int bh = blockIdx.x;
    for (int i = threadIdx.x; i < D_ * (VTS_ - N_); i += 256) {
        int d = i / (VTS_ - N_), m = N_ + i % (VTS_ - N_);
        vtb[((size_t)bh * D_ + d) * VTS_ + m] = 0;
    }
}

// ---------------------------------------------------------------------------
// MFMA attention, S^T orientation: lane = q-row n (col), registers = key m.
// QK^T = mfma(kf, qf); bias = 22x 8B rpb loads + 3x uint4 mask-bit loads per
// lane; softmax in-lane + 2 quad shuffles; P rows written m-contiguous (b64);
// PV = mfma(vf, pf) -> O^T, packed 8B output stores.
// ---------------------------------------------------------------------------
__global__ __launch_bounds__(256, 2) void attn_mfma(
    const ushort_t* __restrict__ qb, const ushort_t* __restrict__ kb,
    const ushort_t* __restrict__ vtb, const ushort_t* __restrict__ rpbb,
    const unsigned int* __restrict__ mbits, ushort_t* __restrict__ aob)
{
    __shared__ ushort_t smem[24064];   // union: ks[352][40] 28160B / pbuf[4][16][376] 48128B
    ushort_t* ks = smem;
    ushort_t* pb = smem;

    const int t = threadIdx.x, wv = t >> 6, lane = t & 63;
    const int quad = lane >> 4, col = lane & 15;
    const int qt = blockIdx.x, h = blockIdx.y, b = blockIdx.z;
    const int bh = b * H_ + h;
    const int w  = b & (NW_ - 1);
    const int n0 = qt * 64 + wv * 16;

    // stage K tile [m][d], row stride 40 elems (2-way banks, free)
    const ushort_t* kbase = kb + (size_t)bh * (N_ * D_);
    for (int c = t; c < (N_ * D_) / 8; c += 256) {
        int row = c >> 2, off = (c & 3) * 8;
        *(short8*)(ks + row * 40 + off) = *(const short8*)(kbase + c * 8);
    }

    int nn = n0 + col; if (nn > N_ - 1) nn = N_ - 1;   // tail clamp (stores gated)
    short8 qf = *(const short8*)(qb + ((size_t)bh * N_ + nn) * D_ + quad * 8);

    // per-lane bias metadata (independent of MFMA -> overlaps)
    const unsigned int* mbp = mbits + ((size_t)w * N_ + nn) * 12;
    uint4 mc0 = *(const uint4*)mbp;
    uint4 mc1 = *(const uint4*)(mbp + 4);
    uint4 mc2 = *(const uint4*)(mbp + 8);
    unsigned int dwv[12] = {mc0.x,mc0.y,mc0.z,mc0.w, mc1.x,mc1.y,mc1.z,mc1.w, mc2.x,mc2.y,mc2.z,mc2.w};
    const ushort_t* rpn = rpbb + (size_t)h * (N_ * RPS_) + (size_t)nn * RPS_;

    __syncthreads();

    // QK^T -> S^T tiles: D[row=m-sub][col=n]
    f32x4 sacc[22];
    #pragma unroll
    for (int kt = 0; kt < 22; ++kt) {
        short8 kf = *(const short8*)(ks + (kt * 16 + col) * 40 + quad * 8);
        sacc[kt] = __builtin_amdgcn_mfma_f32_16x16x32_bf16(kf, qf, (f32x4){0.f,0.f,0.f,0.f}, 0, 0, 0);
    }
    __syncthreads();   // ks dead; pbuf may overwrite

    // bias: vectorized rpb (8B) + mask nibble; masked/pad -> -3e38 (replaces junk)
    #pragma unroll
    for (int kt = 0; kt < 22; ++kt) {
        int mb4 = kt * 16 + quad * 4;
        uint2 rv = *(const uint2*)(rpn + mb4);
        unsigned int nib = (dwv[kt >> 1] >> (((kt & 1) << 4) + (quad << 2))) & 0xFu;
        float b0 = b2f(rv.x & 0xffffu), b1 = b2f(rv.x >> 16);
        float b2v = b2f(rv.y & 0xffffu), b3 = b2f(rv.y >> 16);
        sacc[kt][0] = (nib & 1u) ? sacc[kt][0] + b0 : -3.0e38f;
        sacc[kt][1] = (nib & 2u) ? sacc[kt][1] + b1 : -3.0e38f;
        sacc[kt][2] = (nib & 4u) ? sacc[kt][2] + b2v : -3.0e38f;
        sacc[kt][3] = (nib & 8u) ? sacc[kt][3] + b3 : -3.0e38f;
    }

    // softmax: in-lane (88 vals) + quad butterfly (lanes col, col+16, col+32, col+48)
    f32x4 m4 = sacc[0];
    #pragma unroll
    for (int kt = 1; kt < 22; ++kt) {
        m4[0] = fmaxf(m4[0], sacc[kt][0]); m4[1] = fmaxf(m4[1], sacc[kt][1]);
        m4[2] = fmaxf(m4[2], sacc[kt][2]); m4[3] = fmaxf(m4[3], sacc[kt][3]);
    }
    float mx = fmaxf(fmaxf(m4[0], m4[1]), fmaxf(m4[2], m4[3]));
    mx = fmaxf(mx, __shfl_xor(mx, 16));
    mx = fmaxf(mx, __shfl_xor(mx, 32));

    ushort_t* prow = pb + (size_t)(wv * 16 + col) * PBS_;
    float sum = 0.f;
    #pragma unroll
    for (int kt = 0; kt < 22; ++kt) {
        float e0 = __expf(sacc[kt][0] - mx), e1 = __expf(sacc[kt][1] - mx);
        float e2 = __expf(sacc[kt][2] - mx), e3 = __expf(sacc[kt][3] - mx);
        sum += (e0 + e1) + (e2 + e3);
        uint2 pk;
        pk.x = f2b(e0) | (f2b(e1) << 16);
        pk.y = f2b(e2) | (f2b(e3) << 16);
        *(uint2*)(prow + kt * 16 + quad * 4) = pk;   // own wave's region; lgkm-ordered
    }
    sum += __shfl_xor(sum, 16);
    sum += __shfl_xor(sum, 32);

    // PV: O^T = V^T . P^T ; A = vtb rows (16B), B = pbuf rows (16B)
    const ushort_t* vbase = vtb + (size_t)bh * (D_ * VTS_);
    f32x4 oa = {0.f,0.f,0.f,0.f}, ob = {0.f,0.f,0.f,0.f};
    #pragma unroll
    for (int mt = 0; mt < 11; ++mt) {
        short8 pf = *(const short8*)(prow + mt * 32 + quad * 8);
        short8 v0 = *(const short8*)(vbase + (size_t)col * VTS_ + mt * 32 + quad * 8);
        short8 v1 = *(const short8*)(vbase + (size_t)(col + 16) * VTS_ + mt * 32 + quad * 8);
        oa = __builtin_amdgcn_mfma_f32_16x16x32_bf16(v0, pf, oa, 0, 0, 0);
        ob = __builtin_amdgcn_mfma_f32_16x16x32_bf16(v1, pf, ob, 0, 0, 0);
    }

    // store O^T: d = quad*4+r (+16), n = col lane; 2x 8B packed stores
    int n = n0 + col;
    if (n < N_) {
        float inv = 1.0f / sum;
        ushort_t* op = aob + ((size_t)b * N_ + n) * C_ + h * D_;
        uint2 p0, p1;
        p0.x = f2b(oa[0] * inv) | (f2b(oa[1] * inv) << 16);
        p0.y = f2b(oa[2] * inv) | (f2b(oa[3] * inv) << 16);
        p1.x = f2b(ob[0] * inv) | (f2b(ob[1] * inv) << 16);
        p1.y = f2b(ob[2] * inv) | (f2b(ob[3] * inv) << 16);
        *(uint2*)(op + quad * 4) = p0;
        *(uint2*)(op + 16 + quad * 4) = p1;
    }
}

// ---------------------------------------------------------------------------
extern "C" void kernel_launch(void* const* d_in, const int* in_sizes, int n_in,
                              void* d_out, int out_size, void* d_ws, size_t ws_size,
                              hipStream_t stream)
{
    const float* x_q    = (const float*)d_in[0];
    const float* x_kv   = (const float*)d_in[1];
    const float* mask   = (const float*)d_in[2];
    const float* q_w    = (const float*)d_in[3];
    const float* q_b    = (const float*)d_in[4];
    const float* kv_w   = (const float*)d_in[5];
    const float* kv_b   = (const float*)d_in[6];
    const float* proj_w = (const float*)d_in[7];
    const float* proj_b = (const float*)d_in[8];
    const float* rpb_t  = (const float*)d_in[9];
    const int*   rpi    = (const int*)d_in[10];
    float* out = (float*)d_out;

    // ws: qx 33.7 | kx 33.7 | vtb 34.6 | aob 33.7 | rpbb 1.42 | wb 0.29 | mbits 1.05 MB
    const size_t QKV  = (size_t)B_ * H_ * N_ * D_;       // 16,859,136
    const size_t QKV2 = (size_t)B_ * H_ * D_ * VTS_;     // 17,301,504
    char* ws = (char*)d_ws;
    ushort_t* qx   = (ushort_t*)ws;
    ushort_t* kx   = qx + QKV;
    ushort_t* vtb  = kx + QKV;
    ushort_t* aob  = vtb + QKV2;
    ushort_t* rpbb = aob + QKV;
    ushort_t* wb   = rpbb + ((size_t)H_ * N_ * RPS_ + 16);   // +16 tail pad (OOB-read guard)
    unsigned int* mbits = (unsigned int*)(wb + 147456);

    wcvt<<<144, 256, 0, stream>>>(q_w, kv_w, proj_w, wb);
    rpb_gather_b<<<N_, 256, 0, stream>>>(rpb_t, rpi, rpbb);
    mask_bits<<<(NW_ * N_ * 6) / 4, 256, 0, stream>>>(mask, mbits);
    vt_pad<<<B_ * H_, 256, 0, stream>>>(vtb);
    gemm_qkv<<<dim3(M_/128, 3), 256, 0, stream>>>(
        x_q, x_kv, wb, q_b, kv_b, qx, kx, vtb);
    attn_mfma<<<dim3(6, H_, B_), 256, 0, stream>>>(qx, kx, vtb, rpbb, mbits, aob);
    gemm_out<<<M_/128, 256, 0, stream>>>(aob, wb, proj_b, out);
}